// Round 3
// baseline (1510.122 us; speedup 1.0000x reference)
//
#include <hip/hip_runtime.h>
#include <hip/hip_cooperative_groups.h>
#include <cstdint>
#include <cstddef>

namespace cg = cooperative_groups;

// GCN via associativity: relu((A@H)@W^T) == relu(A@(H@W^T)).
// Single persistent cooperative kernel, phases separated by grid.sync():
//   P1: PT1=(X W1^T)^T   S1: part=A@P1 (fp32 A -> save bf16 copy)
//   P2: PT2=(relu(sum part) W2^T)^T   S2: part=A@P2 (bf16 A)
//   P3: PT3                           S3: part=A@P3 (bf16 A)
//   RED: out = sum part
// k-slot permutation (A and B agree; bijection cancels in MFMA dot):
//   stored pos p(k) = ((k&15)>>2)*8 + (k&3) + ((k>>4)<<2) within each 32-k group.

#define NN 16384
#define SK1 8
#define KC1 (NN / SK1)   // 2048
#define SK2 16
#define KC2 (NN / SK2)   // 1024

typedef __attribute__((ext_vector_type(8))) short s16x8;
typedef __attribute__((ext_vector_type(4))) float fx4;

__device__ __forceinline__ unsigned short f2bf_rne(float f) {
    unsigned int x = __builtin_bit_cast(unsigned int, f);
    x += 0x7fffu + ((x >> 16) & 1u);
    return (unsigned short)(x >> 16);
}

__device__ __forceinline__ s16x8 pack_bf(fx4 a, fx4 b) {
    s16x8 t;
    t[0] = (short)f2bf_rne(a[0]);
    t[1] = (short)f2bf_rne(a[1]);
    t[2] = (short)f2bf_rne(a[2]);
    t[3] = (short)f2bf_rne(a[3]);
    t[4] = (short)f2bf_rne(b[0]);
    t[5] = (short)f2bf_rne(b[1]);
    t[6] = (short)f2bf_rne(b[2]);
    t[7] = (short)f2bf_rne(b[3]);
    return t;
}

// ---------------- projection: PT[c][perm(r)] = bf16(act(H[r,:]) @ W[c,:]) ----
template <int DIN, int DOUT, int NSUM, bool RELU>
__device__ __forceinline__ void proj_phase(
    const float* __restrict__ src, const float* __restrict__ W,
    unsigned short* __restrict__ PT, float* Ws, float* Hs,
    int nblk, int bid, int tid)
{
    for (int i = tid; i < DOUT * DIN; i += 256) Ws[i] = W[i];
    for (int rb = bid; rb < NN / 16; rb += nblk) {
        const int rbase = rb * 16;
        __syncthreads();   // Ws ready (1st iter) / Hs consumers done (later iters)
        for (int i = tid; i < 16 * DIN; i += 256) {
            const int rl = i / DIN, k = i % DIN;
            float v = 0.f;
#pragma unroll
            for (int s2 = 0; s2 < NSUM; ++s2)
                v += src[(long)s2 * NN * DIN + (long)(rbase + rl) * DIN + k];
            Hs[rl * 65 + k] = RELU ? fmaxf(v, 0.f) : v;
        }
        __syncthreads();
        const int rl = tid & 15;
        const int r = rbase + rl;
        const int kk = r & 31;
        const int pidx = (r & ~31) + ((kk & 15) >> 2) * 8 + (kk & 3) + ((kk >> 4) << 2);
        for (int c = tid >> 4; c < DOUT; c += 16) {
            float acc = 0.f;
#pragma unroll
            for (int k = 0; k < DIN; ++k) acc += Hs[rl * 65 + k] * Ws[c * DIN + k];
            PT[(long)c * NN + pidx] = f2bf_rne(acc);
        }
    }
}

// ---------------- S1: part[s] = A@P1 (D=64), fp32 A read (+bf16 save) --------
template <int SAVE>
__device__ __forceinline__ void spmm1_phase(
    const float* __restrict__ A32, unsigned short* __restrict__ Abf,
    const unsigned short* __restrict__ PT, float* __restrict__ part,
    int nblk, int bid, int wv, int srow, int kg)
{
    for (int wu = bid; wu < (NN / 128) * SK1; wu += nblk) {
        const int rb = wu & (NN / 128 - 1);
        const int s  = wu >> 7;
        const long kbeg = (long)s * KC1;
        const int rowbase = rb * 128 + wv * 32;
        const long r0 = rowbase + srow;
        const long r1 = rowbase + 16 + srow;

        fx4 acc0[4], acc1[4];
#pragma unroll
        for (int c = 0; c < 4; ++c) {
            acc0[c] = (fx4){0.f, 0.f, 0.f, 0.f};
            acc1[c] = (fx4){0.f, 0.f, 0.f, 0.f};
        }
#pragma unroll 2
        for (int i = 0; i < KC1 / 32; ++i) {
            const long ko = kbeg + (long)i * 32;
            const float* p0 = A32 + r0 * (long)NN + ko + kg * 4;
            const float* p1 = A32 + r1 * (long)NN + ko + kg * 4;
            fx4 a00 = __builtin_nontemporal_load((const fx4*)p0);
            fx4 a01 = __builtin_nontemporal_load((const fx4*)(p0 + 16));
            fx4 a10 = __builtin_nontemporal_load((const fx4*)p1);
            fx4 a11 = __builtin_nontemporal_load((const fx4*)(p1 + 16));
            s16x8 af0 = pack_bf(a00, a01);
            s16x8 af1 = pack_bf(a10, a11);
            if (SAVE) {
                __builtin_nontemporal_store(af0, (s16x8*)(Abf + r0 * (long)NN + ko + kg * 8));
                __builtin_nontemporal_store(af1, (s16x8*)(Abf + r1 * (long)NN + ko + kg * 8));
            }
#pragma unroll
            for (int c = 0; c < 4; ++c) {
                s16x8 bf = *(const s16x8*)(PT + (long)(c * 16 + srow) * NN + ko + kg * 8);
                acc0[c] = __builtin_amdgcn_mfma_f32_16x16x32_bf16(af0, bf, acc0[c], 0, 0, 0);
                acc1[c] = __builtin_amdgcn_mfma_f32_16x16x32_bf16(af1, bf, acc1[c], 0, 0, 0);
            }
        }
        // C layout: col = lane&15, row = (lane>>4)*4 + reg
        float* pbase = part + (long)s * NN * 64;
#pragma unroll
        for (int c = 0; c < 4; ++c)
#pragma unroll
            for (int r = 0; r < 4; ++r) {
                pbase[(long)(rowbase + kg * 4 + r) * 64 + c * 16 + srow]      = acc0[c][r];
                pbase[(long)(rowbase + 16 + kg * 4 + r) * 64 + c * 16 + srow] = acc1[c][r];
            }
    }
}

// ---------------- S2/S3: part[s] = A@P (D=32), 4 row-tiles/wave --------------
template <int ABF>   // 1: bf16 A copy; 0: fp32 A (fallback, no save)
__device__ __forceinline__ void spmm2_phase(
    const unsigned short* __restrict__ Abf, const float* __restrict__ A32,
    const unsigned short* __restrict__ PT, float* __restrict__ part,
    int nblk, int bid, int wv, int srow, int kg)
{
    for (int wu = bid; wu < (NN / 256) * SK2; wu += nblk) {
        const int rb = wu & (NN / 256 - 1);
        const int s  = wu >> 6;
        const long kbeg = (long)s * KC2;
        const int rowbase = rb * 256 + wv * 64;

        fx4 acc[4][2];
#pragma unroll
        for (int t = 0; t < 4; ++t)
#pragma unroll
            for (int c = 0; c < 2; ++c) acc[t][c] = (fx4){0.f, 0.f, 0.f, 0.f};

#pragma unroll 2
        for (int i = 0; i < KC2 / 32; ++i) {
            const long ko = kbeg + (long)i * 32;
            s16x8 af[4];
            if (ABF) {
#pragma unroll
                for (int t = 0; t < 4; ++t)
                    af[t] = *(const s16x8*)(Abf + (long)(rowbase + t * 16 + srow) * NN + ko + kg * 8);
            } else {
#pragma unroll
                for (int t = 0; t < 4; ++t) {
                    const float* p = A32 + (long)(rowbase + t * 16 + srow) * NN + ko + kg * 4;
                    fx4 a0 = __builtin_nontemporal_load((const fx4*)p);
                    fx4 a1 = __builtin_nontemporal_load((const fx4*)(p + 16));
                    af[t] = pack_bf(a0, a1);
                }
            }
            s16x8 b0 = *(const s16x8*)(PT + (long)srow * NN + ko + kg * 8);
            s16x8 b1 = *(const s16x8*)(PT + (long)(16 + srow) * NN + ko + kg * 8);
#pragma unroll
            for (int t = 0; t < 4; ++t) {
                acc[t][0] = __builtin_amdgcn_mfma_f32_16x16x32_bf16(af[t], b0, acc[t][0], 0, 0, 0);
                acc[t][1] = __builtin_amdgcn_mfma_f32_16x16x32_bf16(af[t], b1, acc[t][1], 0, 0, 0);
            }
        }
        float* pbase = part + (long)s * NN * 32;
#pragma unroll
        for (int t = 0; t < 4; ++t)
#pragma unroll
            for (int c = 0; c < 2; ++c)
#pragma unroll
                for (int r = 0; r < 4; ++r)
                    pbase[(long)(rowbase + t * 16 + kg * 4 + r) * 32 + c * 16 + srow] = acc[t][c][r];
    }
}

// ---------------- RED: out = sum_s part[s] -----------------------------------
__device__ __forceinline__ void red_phase(
    const float* __restrict__ part, float* __restrict__ out, int nthr, int gtid)
{
    for (int e = gtid; e < NN * 32 / 4; e += nthr) {
        fx4 v = (fx4){0.f, 0.f, 0.f, 0.f};
#pragma unroll
        for (int s = 0; s < SK2; ++s)
            v += *(const fx4*)(part + (long)s * NN * 32 + (long)e * 4);
        *(fx4*)(out + (long)e * 4) = v;
    }
}

// ---------------- fused kernel -----------------------------------------------
template <int SAVE>
__global__ __launch_bounds__(256, 4) void gcn_fused(
    const float* __restrict__ A32, const float* __restrict__ X,
    const float* __restrict__ W1, const float* __restrict__ W2,
    const float* __restrict__ W3, float* __restrict__ out,
    float* __restrict__ part, unsigned short* __restrict__ PT,
    unsigned short* __restrict__ Abf)
{
    __shared__ float Ws[64 * 64];
    __shared__ float Hs[16 * 65];
    cg::grid_group g = cg::this_grid();
    const int tid = threadIdx.x, bid = blockIdx.x, nblk = gridDim.x;
    const int lane = tid & 63, wv = tid >> 6;
    const int srow = lane & 15, kg = lane >> 4;

    proj_phase<64, 64, 1, false>(X, W1, PT, Ws, Hs, nblk, bid, tid);
    __threadfence(); g.sync();
    spmm1_phase<SAVE>(A32, Abf, PT, part, nblk, bid, wv, srow, kg);
    __threadfence(); g.sync();
    proj_phase<64, 32, SK1, true>(part, W2, PT, Ws, Hs, nblk, bid, tid);
    __threadfence(); g.sync();
    spmm2_phase<SAVE>(Abf, A32, PT, part, nblk, bid, wv, srow, kg);
    __threadfence(); g.sync();
    proj_phase<32, 32, SK2, true>(part, W3, PT, Ws, Hs, nblk, bid, tid);
    __threadfence(); g.sync();
    spmm2_phase<SAVE>(Abf, A32, PT, part, nblk, bid, wv, srow, kg);
    __threadfence(); g.sync();
    red_phase(part, out, nblk * 256, bid * 256 + tid);
}

extern "C" void kernel_launch(void* const* d_in, const int* in_sizes, int n_in,
                              void* d_out, int out_size, void* d_ws, size_t ws_size,
                              hipStream_t stream) {
    const float* A  = (const float*)d_in[0];
    const float* X  = (const float*)d_in[1];
    const float* W1 = (const float*)d_in[2];
    const float* W2 = (const float*)d_in[3];
    const float* W3 = (const float*)d_in[4];
    float* out = (float*)d_out;

    char* ws = (char*)d_ws;
    const size_t part_b = (size_t)SK2 * NN * 32 * 4;   // 32 MiB (== SK1*NN*64*4)
    const size_t pt_b   = (size_t)64 * NN * 2;         //  2 MiB
    const size_t abf_b  = (size_t)NN * NN * 2;         // 512 MiB
    float*          part = (float*)ws;
    unsigned short* PT   = (unsigned short*)(ws + part_b);
    unsigned short* Abf  = (unsigned short*)(ws + part_b + pt_b);
    const bool save = ws_size >= part_b + pt_b + abf_b;

    int maxb = 0;
    if (save) hipOccupancyMaxActiveBlocksPerMultiprocessor(&maxb, gcn_fused<1>, 256, 0);
    else      hipOccupancyMaxActiveBlocksPerMultiprocessor(&maxb, gcn_fused<0>, 256, 0);
    if (maxb < 1) maxb = 1;
    long cap = (long)maxb * 256;
    int grid = (int)(cap < 1024 ? cap : 1024);

    void* args[] = {(void*)&A, (void*)&X, (void*)&W1, (void*)&W2, (void*)&W3,
                    (void*)&out, (void*)&part, (void*)&PT, (void*)&Abf};
    if (save)
        hipLaunchCooperativeKernel(gcn_fused<1>, dim3(grid), dim3(256), args, 0, stream);
    else
        hipLaunchCooperativeKernel(gcn_fused<0>, dim3(grid), dim3(256), args, 0, stream);
}

// Round 4
// 689.509 us; speedup vs baseline: 2.1901x; 2.1901x over previous
//
#include <hip/hip_runtime.h>
#include <cstdint>
#include <cstddef>

// GCN via associativity: relu((A@H)@W^T) == relu(A@(H@W^T)).
// Separate kernels (fused coop version regressed: shared VGPR alloc collapsed
// to 56 -> serialized memory). Per layer: tiny proj PT=(H W^T)^T (bf16,
// k-slot-permuted) + split-K tall-skinny MFMA GEMM part=A@P.
// S1 streams fp32 A once (nt), saves bf16 A as MFMA-fragment tiles
// [rowgrp][kblk][lane][8] so S2/S3 load/store are 1KB-dense per instruction;
// Abf uses cached (non-nt) ops so Infinity Cache serves re-reads (round-3
// counters showed L3 absorbs most of the 2x537MB bf16 re-reads).

#define NN 16384
#define SK1 8
#define KC1 (NN / SK1)   // 2048
#define SK2 16
#define KC2 (NN / SK2)   // 1024
#define NKB (NN / 32)    // 512 k-blocks

typedef __attribute__((ext_vector_type(8))) short s16x8;
typedef __attribute__((ext_vector_type(4))) float fx4;

__device__ __forceinline__ unsigned short f2bf_rne(float f) {
    unsigned int x = __builtin_bit_cast(unsigned int, f);
    x += 0x7fffu + ((x >> 16) & 1u);
    return (unsigned short)(x >> 16);
}

__device__ __forceinline__ s16x8 pack_bf(fx4 a, fx4 b) {
    s16x8 t;
    t[0] = (short)f2bf_rne(a[0]);
    t[1] = (short)f2bf_rne(a[1]);
    t[2] = (short)f2bf_rne(a[2]);
    t[3] = (short)f2bf_rne(a[3]);
    t[4] = (short)f2bf_rne(b[0]);
    t[5] = (short)f2bf_rne(b[1]);
    t[6] = (short)f2bf_rne(b[2]);
    t[7] = (short)f2bf_rne(b[3]);
    return t;
}

// ---------------------------------------------------------------------------
// S1: part[s] = A@P1 (D=64). fp32 A (nt) -> bf16 frag-tiled copy (cached).
// 2 row-tiles/wave. grid (NN/128, SK1).
// ---------------------------------------------------------------------------
template <int SAVE>
__global__ __launch_bounds__(256, 4) void k_spmm1(
    const float* __restrict__ A32,
    unsigned short* __restrict__ Abf,        // [NN/16][NKB][64][8] bf16 tiles
    const unsigned short* __restrict__ PT,   // [64][NN] bf16, slot-permuted
    float* __restrict__ part)                // [SK1][NN][64] f32
{
    const int lane = threadIdx.x & 63;
    const int wv   = threadIdx.x >> 6;
    const int srow = lane & 15;
    const int kg   = lane >> 4;
    const int s    = blockIdx.y;
    const long kbeg = (long)s * KC1;
    const int rowbase = blockIdx.x * 128 + wv * 32;
    const long r0 = rowbase + srow;
    const long r1 = rowbase + 16 + srow;
    const long g0 = rowbase >> 4, g1 = g0 + 1;

    fx4 acc0[4], acc1[4];
#pragma unroll
    for (int c = 0; c < 4; ++c) {
        acc0[c] = (fx4){0.f, 0.f, 0.f, 0.f};
        acc1[c] = (fx4){0.f, 0.f, 0.f, 0.f};
    }

#pragma unroll 2
    for (int i = 0; i < KC1 / 32; ++i) {
        const long ko = kbeg + (long)i * 32;
        const long kblk = ko >> 5;
        const float* p0 = A32 + r0 * (long)NN + ko + kg * 4;
        const float* p1 = A32 + r1 * (long)NN + ko + kg * 4;
        fx4 a00 = __builtin_nontemporal_load((const fx4*)p0);
        fx4 a01 = __builtin_nontemporal_load((const fx4*)(p0 + 16));
        fx4 a10 = __builtin_nontemporal_load((const fx4*)p1);
        fx4 a11 = __builtin_nontemporal_load((const fx4*)(p1 + 16));
        s16x8 af0 = pack_bf(a00, a01);
        s16x8 af1 = pack_bf(a10, a11);
        if (SAVE) {
            *(s16x8*)(Abf + ((g0 * NKB + kblk) * 64 + lane) * 8) = af0;
            *(s16x8*)(Abf + ((g1 * NKB + kblk) * 64 + lane) * 8) = af1;
        }
#pragma unroll
        for (int c = 0; c < 4; ++c) {
            s16x8 bf = *(const s16x8*)(PT + (long)(c * 16 + srow) * NN + ko + kg * 8);
            acc0[c] = __builtin_amdgcn_mfma_f32_16x16x32_bf16(af0, bf, acc0[c], 0, 0, 0);
            acc1[c] = __builtin_amdgcn_mfma_f32_16x16x32_bf16(af1, bf, acc1[c], 0, 0, 0);
        }
    }
    // C layout: col = lane&15, row = (lane>>4)*4 + reg
    float* pbase = part + (long)s * NN * 64;
#pragma unroll
    for (int c = 0; c < 4; ++c)
#pragma unroll
        for (int r = 0; r < 4; ++r) {
            pbase[(long)(rowbase + kg * 4 + r) * 64 + c * 16 + srow]      = acc0[c][r];
            pbase[(long)(rowbase + 16 + kg * 4 + r) * 64 + c * 16 + srow] = acc1[c][r];
        }
}

// ---------------------------------------------------------------------------
// S2/S3: part[s] = A@P (D=32). 4 row-tiles/wave, frag-tiled bf16 A (1KB-dense).
// grid (NN/256, SK2).
// ---------------------------------------------------------------------------
template <int ABF>
__global__ __launch_bounds__(256, 4) void k_spmm2(
    const unsigned short* __restrict__ Abf,
    const float* __restrict__ A32,
    const unsigned short* __restrict__ PT,   // [32][NN]
    float* __restrict__ part)                // [SK2][NN][32]
{
    const int lane = threadIdx.x & 63;
    const int wv   = threadIdx.x >> 6;
    const int srow = lane & 15;
    const int kg   = lane >> 4;
    const int s    = blockIdx.y;
    const long kbeg = (long)s * KC2;
    const int rowbase = blockIdx.x * 256 + wv * 64;
    const long g0 = rowbase >> 4;

    fx4 acc[4][2];
#pragma unroll
    for (int t = 0; t < 4; ++t)
#pragma unroll
        for (int c = 0; c < 2; ++c) acc[t][c] = (fx4){0.f, 0.f, 0.f, 0.f};

#pragma unroll 2
    for (int i = 0; i < KC2 / 32; ++i) {
        const long ko = kbeg + (long)i * 32;
        const long kblk = ko >> 5;
        s16x8 af[4];
        if (ABF) {
#pragma unroll
            for (int t = 0; t < 4; ++t)
                af[t] = *(const s16x8*)(Abf + (((g0 + t) * NKB + kblk) * 64 + lane) * 8);
        } else {
#pragma unroll
            for (int t = 0; t < 4; ++t) {
                const float* p = A32 + (long)(rowbase + t * 16 + srow) * NN + ko + kg * 4;
                fx4 a0 = __builtin_nontemporal_load((const fx4*)p);
                fx4 a1 = __builtin_nontemporal_load((const fx4*)(p + 16));
                af[t] = pack_bf(a0, a1);
            }
        }
        s16x8 b0 = *(const s16x8*)(PT + (long)srow * NN + ko + kg * 8);
        s16x8 b1 = *(const s16x8*)(PT + (long)(16 + srow) * NN + ko + kg * 8);
#pragma unroll
        for (int t = 0; t < 4; ++t) {
            acc[t][0] = __builtin_amdgcn_mfma_f32_16x16x32_bf16(af[t], b0, acc[t][0], 0, 0, 0);
            acc[t][1] = __builtin_amdgcn_mfma_f32_16x16x32_bf16(af[t], b1, acc[t][1], 0, 0, 0);
        }
    }
    float* pbase = part + (long)s * NN * 32;
#pragma unroll
    for (int t = 0; t < 4; ++t)
#pragma unroll
        for (int c = 0; c < 2; ++c)
#pragma unroll
            for (int r = 0; r < 4; ++r)
                pbase[(long)(rowbase + t * 16 + kg * 4 + r) * 32 + c * 16 + srow] = acc[t][c][r];
}

// ---------------------------------------------------------------------------
// Projection: PT[c][perm(r)] = bf16( act(H[r,:]) @ W[c,:] )
// ---------------------------------------------------------------------------
template <int DIN, int DOUT, int NSUM, bool RELU>
__global__ __launch_bounds__(256) void k_proj(
    const float* __restrict__ src,     // [NSUM][NN][DIN]
    const float* __restrict__ W,       // [DOUT][DIN]
    unsigned short* __restrict__ PT)   // [DOUT][NN] slot-permuted
{
    __shared__ float Ws[DOUT * DIN];
    __shared__ float Hs[64][DIN + 1];
    const int tid = threadIdx.x;
    for (int i = tid; i < DOUT * DIN; i += 256) Ws[i] = W[i];
    const int rbase = blockIdx.x * 64;
    for (int i = tid; i < 64 * DIN; i += 256) {
        const int rl = i / DIN, k = i % DIN;
        float v = 0.f;
#pragma unroll
        for (int s2 = 0; s2 < NSUM; ++s2)
            v += src[(long)s2 * NN * DIN + (long)(rbase + rl) * DIN + k];
        Hs[rl][k] = RELU ? fmaxf(v, 0.f) : v;
    }
    __syncthreads();
    const int rl = tid & 63;
    const int c0 = tid >> 6;
    const int r  = rbase + rl;
    const int kk = r & 31;
    const int pidx = (r & ~31) + ((kk & 15) >> 2) * 8 + (kk & 3) + ((kk >> 4) << 2);
    for (int c = c0; c < DOUT; c += 4) {
        float accv = 0.f;
#pragma unroll
        for (int k = 0; k < DIN; ++k) accv += Hs[rl][k] * Ws[c * DIN + k];
        PT[(long)c * NN + pidx] = f2bf_rne(accv);
    }
}

// Final reduce: out[NN][32] = sum_s part[s]
__global__ __launch_bounds__(256) void k_red(
    const float* __restrict__ part, float* __restrict__ out)
{
    const int e = blockIdx.x * 256 + threadIdx.x;
    if (e >= NN * 32 / 4) return;
    fx4 v = (fx4){0.f, 0.f, 0.f, 0.f};
#pragma unroll
    for (int s = 0; s < SK2; ++s)
        v += *(const fx4*)(part + (long)s * NN * 32 + (long)e * 4);
    *(fx4*)(out + (long)e * 4) = v;
}

extern "C" void kernel_launch(void* const* d_in, const int* in_sizes, int n_in,
                              void* d_out, int out_size, void* d_ws, size_t ws_size,
                              hipStream_t stream) {
    const float* A  = (const float*)d_in[0];
    const float* X  = (const float*)d_in[1];
    const float* W1 = (const float*)d_in[2];
    const float* W2 = (const float*)d_in[3];
    const float* W3 = (const float*)d_in[4];
    float* out = (float*)d_out;

    char* ws = (char*)d_ws;
    const size_t part_b = (size_t)SK1 * NN * 64 * 4;   // 32 MiB (== SK2*NN*32*4)
    const size_t pt_b   = (size_t)64 * NN * 2;         //  2 MiB
    const size_t abf_b  = (size_t)NN * NN * 2;         // 512 MiB
    float*          part = (float*)ws;
    unsigned short* PT   = (unsigned short*)(ws + part_b);
    unsigned short* Abf  = (unsigned short*)(ws + part_b + pt_b);
    const bool save = ws_size >= part_b + pt_b + abf_b;

    dim3 b(256);
    dim3 gP(NN / 64);
    dim3 g1(NN / 128, SK1);
    dim3 g2(NN / 256, SK2);

    // Layer 1
    k_proj<64, 64, 1, false><<<gP, b, 0, stream>>>(X, W1, PT);
    if (save) k_spmm1<1><<<g1, b, 0, stream>>>(A, Abf, PT, part);
    else      k_spmm1<0><<<g1, b, 0, stream>>>(A, Abf, PT, part);

    // Layer 2
    k_proj<64, 32, SK1, true><<<gP, b, 0, stream>>>(part, W2, PT);
    if (save) k_spmm2<1><<<g2, b, 0, stream>>>(Abf, A, PT, part);
    else      k_spmm2<0><<<g2, b, 0, stream>>>(Abf, A, PT, part);

    // Layer 3
    k_proj<32, 32, SK2, true><<<gP, b, 0, stream>>>(part, W3, PT);
    if (save) k_spmm2<1><<<g2, b, 0, stream>>>(Abf, A, PT, part);
    else      k_spmm2<0><<<g2, b, 0, stream>>>(Abf, A, PT, part);

    k_red<<<dim3(NN * 32 / 4 / 256), b, 0, stream>>>(part, out);
}